// Round 6
// baseline (848.142 us; speedup 1.0000x reference)
//
#include <hip/hip_runtime.h>

typedef unsigned short u16;
typedef unsigned int u32;
typedef __attribute__((ext_vector_type(8))) short bf16x8;
typedef __attribute__((ext_vector_type(4))) float f32x4;

#define NB 4
#define NVOX 8192
#define GD 50
#define PZ 52
#define CELLS 125000

// ---- workspace layout (bytes) ----
#define OWNER_OFF 0u            // int32[4*125000] = 2,000,000
#define STATS_OFF 2000000u      // f32[768]
#define WT1_OFF   2003072u      // bf16 27*64*128 frag-linear = 442,368
#define WT2_OFF   2445440u      // bf16 27*128*64 frag-linear = 442,368
#define VW2F_OFF  2887808u      // bf16 8*128*8  = 16,384 (W2^T frag-linear)
#define VW3F_OFF  2904192u      // bf16 16*128*8 = 32,768 (W3^T frag-linear)
#define GRID_OFF  2936960u      // bf16 4*50*50*52*128 = 133,120,000
#define Y1_OFF    136056960u    // bf16 4*50*50*50*64  =  64,000,000
#define ZPAD_OFF  200056960u    // bf16 zero column 52*128*2 = 13,312

#define S1_SUM 0
#define S1_SQ  64
#define SC1    128
#define SH1    192
#define S2_SUM 256
#define S2_SQ  384
#define SC2    512
#define SH2    640

__device__ __forceinline__ float bf2f(u16 v){ union{u32 u; float f;} x; x.u=((u32)v)<<16; return x.f; }
__device__ __forceinline__ u16 f2bf(float f){ union{u32 u; float f;} x; x.f=f; u32 r = x.u + 0x7fffu + ((x.u>>16)&1u); return (u16)(r>>16); }
__device__ __forceinline__ f32x4 fzero(){ f32x4 v; v[0]=0.f; v[1]=0.f; v[2]=0.f; v[3]=0.f; return v; }

#define GLOAD16(g, l) __builtin_amdgcn_global_load_lds( \
    (const __attribute__((address_space(1))) void*)(g), \
    (__attribute__((address_space(3))) void*)(l), 16, 0, 0)

// ---- weight re-layout ----
__global__ void k_wt_transform(const float* __restrict__ k1, const float* __restrict__ k2,
                               const float* __restrict__ W2, const float* __restrict__ W3,
                               u16* __restrict__ wt1, u16* __restrict__ wt2,
                               u16* __restrict__ vw2f, u16* __restrict__ vw3f) {
    int idx = blockIdx.x * 256 + threadIdx.x;
    if (idx < 221184) {
        {
            int j = idx & 7, co = (idx>>3)&63, kq = (idx>>9)&3, kc = (idx>>11)&3, s = idx>>13;
            int ci = kc*32 + kq*8 + j;
            wt1[idx] = f2bf(k1[(co*128 + ci)*27 + s]);
        }
        {
            int j = idx & 7, co = (idx>>3)&127, kq = (idx>>10)&3, kc = (idx>>12)&1, s = idx>>13;
            int ci = kc*32 + kq*8 + j;
            wt2[idx] = f2bf(k2[(co*64 + ci)*27 + s]);
        }
    }
    if (idx < 8192) {
        int j = idx & 7, n = (idx>>3)&127, q = idx>>10;
        vw2f[idx] = f2bf(W2[(q*8+j)*128 + n]);
    }
    if (idx < 16384) {
        int j = idx & 7, n = (idx>>3)&127, q = idx>>10;
        vw3f[idx] = f2bf(W3[(q*8+j)*128 + n]);
    }
}

// ---- duplicate resolution: last-write-wins == max n per cell ----
__global__ void k_owner(const int* __restrict__ coords, int* __restrict__ owner) {
    int v = blockIdx.x * 256 + threadIdx.x;
    if (v >= NB*NVOX) return;
    int b = v >> 13, n = v & (NVOX-1);
    int x = coords[v*3], y = coords[v*3+1], z = coords[v*3+2];
    atomicMax(&owner[b*CELLS + (x*GD + y)*GD + z], n);
}

// ---- VFE via MFMA: 4 voxels (128 points) per block, 4 waves ----
__global__ __launch_bounds__(256, 2) void k_vfe(
        const float* __restrict__ vf, const int* __restrict__ coords,
        const float* __restrict__ W1, const float* __restrict__ b1,
        const float* __restrict__ b2, const float* __restrict__ b3,
        const u16* __restrict__ vw2f, const u16* __restrict__ vw3f,
        const int* __restrict__ owner, u16* __restrict__ grid) {
    const int bid = blockIdx.x;
    const int t = threadIdx.x;
    const int w = t >> 6, lane = t & 63;
    const int lo = lane & 15, hi = lane >> 4;
    const int chgrp = w >> 1, pgrp = w & 1;

    __shared__ __align__(16) char pool[49152];
    u16* h1s = (u16*)pool;                 // [128][64] bf16 swizzled
    char* h2s = pool + 16384;              // [128][128] bf16 swizzled
    float* red = (float*)(pool + 16384);   // [4 vox][16 lo][128 ch] f32 (reuses h2s)

    bf16x8 wa2[2][4], wa3[4][4];
    #pragma unroll
    for (int kk = 0; kk < 2; ++kk)
        #pragma unroll
        for (int cf = 0; cf < 4; ++cf)
            wa2[kk][cf] = *(const bf16x8*)(vw2f + (((kk*4+hi)*128) + chgrp*64 + cf*16 + lo)*8);
    #pragma unroll
    for (int kk = 0; kk < 4; ++kk)
        #pragma unroll
        for (int cf = 0; cf < 4; ++cf)
            wa3[kk][cf] = *(const bf16x8*)(vw3f + (((kk*4+hi)*128) + chgrp*64 + cf*16 + lo)*8);
    f32x4 bb2[4];
    #pragma unroll
    for (int cf = 0; cf < 4; ++cf)
        bb2[cf] = *(const f32x4*)(b2 + chgrp*64 + cf*16 + hi*4);

    {
        const int pt = t & 127, C0 = (t >> 7) * 32;
        f32x4 xv0 = *(const f32x4*)(vf + (size_t)(bid*128 + pt)*8);
        f32x4 xv1 = *(const f32x4*)(vf + (size_t)(bid*128 + pt)*8 + 4);
        float x[8] = {xv0[0],xv0[1],xv0[2],xv0[3],xv1[0],xv1[1],xv1[2],xv1[3]};
        float h[32];
        #pragma unroll
        for (int c = 0; c < 32; ++c) h[c] = b1[C0 + c];
        #pragma unroll
        for (int k = 0; k < 8; ++k) {
            float xk = x[k];
            #pragma unroll
            for (int c = 0; c < 32; ++c) h[c] += xk * W1[k*64 + C0 + c];
        }
        #pragma unroll
        for (int c8 = 0; c8 < 4; ++c8) {
            u16 d8[8];
            #pragma unroll
            for (int j = 0; j < 8; ++j) d8[j] = f2bf(fmaxf(h[c8*8 + j], 0.f));
            int slot = ((C0 >> 3) + c8) ^ (pt & 7);
            *(uint4*)(h1s + pt*64 + slot*8) = *(uint4*)d8;
        }
    }
    __syncthreads();

    f32x4 acc2[4][4];
    #pragma unroll
    for (int cf = 0; cf < 4; ++cf)
        #pragma unroll
        for (int pf = 0; pf < 4; ++pf) acc2[cf][pf] = fzero();
    #pragma unroll
    for (int kk = 0; kk < 2; ++kk) {
        bf16x8 bh[4];
        #pragma unroll
        for (int pf = 0; pf < 4; ++pf) {
            int pt = pgrp*64 + pf*16 + lo;
            bh[pf] = *(const bf16x8*)(h1s + pt*64 + (((kk*4+hi) ^ (pt&7)) << 3));
        }
        #pragma unroll
        for (int cf = 0; cf < 4; ++cf)
            #pragma unroll
            for (int pf = 0; pf < 4; ++pf)
                acc2[cf][pf] = __builtin_amdgcn_mfma_f32_16x16x32_bf16(wa2[kk][cf], bh[pf], acc2[cf][pf], 0, 0, 0);
    }
    #pragma unroll
    for (int cf = 0; cf < 4; ++cf) {
        #pragma unroll
        for (int pf = 0; pf < 4; ++pf) {
            int pt = pgrp*64 + pf*16 + lo;
            float v0 = fmaxf(acc2[cf][pf][0] + bb2[cf][0], 0.f);
            float v1 = fmaxf(acc2[cf][pf][1] + bb2[cf][1], 0.f);
            float v2 = fmaxf(acc2[cf][pf][2] + bb2[cf][2], 0.f);
            float v3 = fmaxf(acc2[cf][pf][3] + bb2[cf][3], 0.f);
            uint2 d;
            d.x = (u32)f2bf(v0) | ((u32)f2bf(v1) << 16);
            d.y = (u32)f2bf(v2) | ((u32)f2bf(v3) << 16);
            int s = (chgrp*8 + cf*2 + (hi>>1)) ^ (pt & 15);
            *(uint2*)(h2s + pt*256 + s*16 + (hi&1)*8) = d;
        }
    }
    __syncthreads();

    f32x4 acc3[4][4];
    #pragma unroll
    for (int cf = 0; cf < 4; ++cf)
        #pragma unroll
        for (int pf = 0; pf < 4; ++pf) acc3[cf][pf] = fzero();
    #pragma unroll
    for (int kk = 0; kk < 4; ++kk) {
        bf16x8 bh[4];
        #pragma unroll
        for (int pf = 0; pf < 4; ++pf) {
            int pt = pgrp*64 + pf*16 + lo;
            bh[pf] = *(const bf16x8*)(h2s + pt*256 + (((kk*4+hi) ^ (pt&15)) << 4));
        }
        #pragma unroll
        for (int cf = 0; cf < 4; ++cf)
            #pragma unroll
            for (int pf = 0; pf < 4; ++pf)
                acc3[cf][pf] = __builtin_amdgcn_mfma_f32_16x16x32_bf16(wa3[kk][cf], bh[pf], acc3[cf][pf], 0, 0, 0);
    }
    __syncthreads();

    #pragma unroll
    for (int vox01 = 0; vox01 < 2; ++vox01) {
        int vv = pgrp*2 + vox01;
        #pragma unroll
        for (int cf = 0; cf < 4; ++cf) {
            f32x4 mx;
            #pragma unroll
            for (int r = 0; r < 4; ++r)
                mx[r] = fmaxf(acc3[cf][vox01*2][r], acc3[cf][vox01*2+1][r]);
            int s4 = (cf*4 + hi) ^ lo;
            *(f32x4*)(red + vv*2048 + lo*128 + chgrp*64 + s4*4) = mx;
        }
    }
    __syncthreads();

    #pragma unroll
    for (int half = 0; half < 2; ++half) {
        int vv = (t >> 7) + half*2;
        int ch = t & 127;
        int cq = (ch & 63) >> 2, e = ch & 3, cg = ch >> 6;
        float m = -3.0e38f;
        #pragma unroll
        for (int lo2 = 0; lo2 < 16; ++lo2)
            m = fmaxf(m, red[vv*2048 + lo2*128 + cg*64 + ((cq ^ lo2) << 2) + e]);
        int gv = bid*4 + vv;
        int b = gv >> 13, n = gv & (NVOX-1);
        int x = coords[gv*3], y = coords[gv*3+1], z = coords[gv*3+2];
        if (owner[b*CELLS + (x*GD + y)*GD + z] == n) {
            size_t gi = ((((size_t)b*GD + x)*GD + y)*PZ + (z+1))*128 + ch;
            grid[gi] = f2bf(m + b3[ch]);
        }
    }
}

// ---- B-frag loader: weights direct from global (L2-resident) to registers ----
__device__ __forceinline__ void load_b1(const u16* __restrict__ wt1, int s, int kc0,
                                        int hi, int lo, bf16x8 dst[2][4]) {
    #pragma unroll
    for (int kk = 0; kk < 2; ++kk)
        #pragma unroll
        for (int nf = 0; nf < 4; ++nf)
            dst[kk][nf] = *(const bf16x8*)(wt1 + (size_t)((s*4 + kc0 + kk)*4 + hi)*512 + (nf*16 + lo)*8);
}

// ---- async column stage: global -> LDS (linear dest, inverse-swizzled source) ----
// Read side uses slot = sl ^ (z&15); since XOR is an involution, loading global
// chunk (z, q^(z&15)) into linear LDS slot (z, q) reproduces the same layout.
__device__ __forceinline__ void stage_col(const u16* __restrict__ grid, const u16* __restrict__ zpad,
                                          int b, int xi, int yi, u16* lds_col, int t) {
    const u16* src = (xi >= 0 && xi < GD && yi >= 0 && yi < GD)
                   ? grid + ((size_t)(b*GD + xi)*GD + yi)*(size_t)(PZ*128) : zpad;
    const int lane = t & 63, w = t >> 6;
    #pragma unroll
    for (int j = 0; j < 4; ++j) {
        int k = w + 4*j;
        if (k < 13) {
            int L = k*64 + lane;
            int z = L >> 4;
            int q = (L & 15) ^ (z & 15);
            GLOAD16(src + (size_t)((z << 4) + q)*8, lds_col + k*512);
        }
    }
}

// ---- conv1 via MFMA: 3x3x3, 128->64, stride 1, pad 1 ----
// Block = 4 oy columns (1 per wave), wave tile 64z x 64co. B streamed from L2
// into regs (dbuf). A staged async via global_load_lds with a column-release
// pipeline: per-wave dy orders free cols {0},{1,3,4},{2,5} after phases 0,1,2
// so 4/6 of dx+1's staging overlaps dx's compute. XCD-chunked block swizzle.
__global__ __launch_bounds__(256, 2) void k_conv1(
        const u16* __restrict__ grid, const u16* __restrict__ wt1,
        const u16* __restrict__ zpad,
        u16* __restrict__ y1, float* __restrict__ stats) {
    const int v = blockIdx.x;
    const int f = (v & 7)*325 + (v >> 3);   // bijective: 2600 % 8 == 0
    const int ox = f % 50;
    const int gq = f / 50;
    const int oyp = gq % 13, b = gq / 13;
    const int t = threadIdx.x;
    const int w = t >> 6, lane = t & 63;
    const int lo = lane & 15, hi = lane >> 4;
    const int oy = oyp*4 + w;
    const int y0 = oyp*4 - 1;

    __shared__ __align__(16) u16 in_s[6*52*128];   // 79,872 B
    __shared__ float red[128];
    if (t < 128) red[t] = 0.f;

    f32x4 acc[4][4];
    #pragma unroll
    for (int mf = 0; mf < 4; ++mf)
        #pragma unroll
        for (int nf = 0; nf < 4; ++nf) acc[mf][nf] = fzero();

    // prologue: stage all 6 columns for dx=0 (xi = ox-1)
    #pragma unroll
    for (int c = 0; c < 6; ++c)
        stage_col(grid, zpad, b, ox - 1, y0 + c, in_s + c*6656, t);
    __syncthreads();   // compiler drains vmcnt(0) before barrier

    for (int dx = 0; dx < 3; ++dx) {
        const int xin = ox + dx;   // xi of dx+1
        #pragma unroll
        for (int p = 0; p < 3; ++p) {
            // per-wave dy order: w0:[0,1,2] w1:[0,2,1] w2:[1,2,0] w3:[0,1,2]
            int dyp;
            if (p == 0)      dyp = (w == 2) ? 1 : 0;
            else if (p == 1) dyp = (w == 0 || w == 3) ? 1 : 2;
            else             dyp = (w == 1) ? 1 : ((w == 2) ? 0 : 2);
            const int col = w + dyp;
            const int s0 = (dx*3 + dyp)*3;
            bf16x8 bb0[2][4], bb1[2][4];
            load_b1(wt1, s0, 0, hi, lo, bb0);
            #pragma unroll
            for (int hs = 0; hs < 6; ++hs) {
                const int dz = hs >> 1, kc0 = (hs & 1)*2;
                if (hs < 5) {
                    const int hs2 = hs + 1;
                    if (hs & 1) load_b1(wt1, s0 + (hs2 >> 1), (hs2 & 1)*2, hi, lo, bb0);
                    else        load_b1(wt1, s0 + (hs2 >> 1), (hs2 & 1)*2, hi, lo, bb1);
                }
                #pragma unroll
                for (int kk = 0; kk < 2; ++kk) {
                    const int kc = kc0 + kk;
                    bf16x8 a[4];
                    #pragma unroll
                    for (int mf = 0; mf < 4; ++mf) {
                        int z = mf*16 + lo + dz; z = (z > 51) ? 51 : z;
                        a[mf] = *(const bf16x8*)(in_s + col*6656 + z*128 + (((kc*4 + hi) ^ (z & 15)) << 3));
                    }
                    #pragma unroll
                    for (int mf = 0; mf < 4; ++mf) {
                        #pragma unroll
                        for (int nf = 0; nf < 4; ++nf) {
                            if (hs & 1)
                                acc[mf][nf] = __builtin_amdgcn_mfma_f32_16x16x32_bf16(a[mf], bb1[kk][nf], acc[mf][nf], 0, 0, 0);
                            else
                                acc[mf][nf] = __builtin_amdgcn_mfma_f32_16x16x32_bf16(a[mf], bb0[kk][nf], acc[mf][nf], 0, 0, 0);
                        }
                    }
                }
            }
            __syncthreads();   // all reads of released cols retired
            if (dx < 2) {      // restage released columns for dx+1 (async)
                if (p == 0) {
                    stage_col(grid, zpad, b, xin, y0 + 0, in_s + 0*6656, t);
                } else if (p == 1) {
                    stage_col(grid, zpad, b, xin, y0 + 1, in_s + 1*6656, t);
                    stage_col(grid, zpad, b, xin, y0 + 3, in_s + 3*6656, t);
                    stage_col(grid, zpad, b, xin, y0 + 4, in_s + 4*6656, t);
                } else {
                    stage_col(grid, zpad, b, xin, y0 + 2, in_s + 2*6656, t);
                    stage_col(grid, zpad, b, xin, y0 + 5, in_s + 5*6656, t);
                }
            }
        }
        if (dx < 2) __syncthreads();   // drain outstanding stages before next dx
    }

    // epilogue: store y1 + stats partials
    if (oy < GD) {
        const size_t colbase = ((size_t)(b*GD + ox)*GD + oy)*50;
        float s[4] = {0.f,0.f,0.f,0.f}, q[4] = {0.f,0.f,0.f,0.f};
        #pragma unroll
        for (int mf = 0; mf < 4; ++mf) {
            #pragma unroll
            for (int r = 0; r < 4; ++r) {
                int o = mf*16 + hi*4 + r;
                if (o < 50) {
                    #pragma unroll
                    for (int nf = 0; nf < 4; ++nf) {
                        float vv = acc[mf][nf][r];
                        y1[(colbase + o)*64 + nf*16 + lo] = f2bf(vv);
                        s[nf] += vv; q[nf] += vv*vv;
                    }
                }
            }
        }
        #pragma unroll
        for (int nf = 0; nf < 4; ++nf) {
            atomicAdd(&red[nf*16 + lo], s[nf]);
            atomicAdd(&red[64 + nf*16 + lo], q[nf]);
        }
    }
    __syncthreads();
    if (t < 64) {
        atomicAdd(&stats[S1_SUM + t], red[t]);
        atomicAdd(&stats[S1_SQ  + t], red[64 + t]);
    }
}

// ---- BN finalize ----
__global__ void k_finalize(float* __restrict__ stats, const float* __restrict__ g,
                           const float* __restrict__ be, int C, float cnt,
                           int st_off, int sc_off, int sh_off) {
    int t = threadIdx.x;
    if (t < C) {
        float mean = stats[st_off + t] / cnt;
        float var  = stats[st_off + C + t] / cnt - mean*mean;
        float inv  = rsqrtf(var + 1e-5f);
        stats[sc_off + t] = g[t]*inv;
        stats[sh_off + t] = be[t] - mean*g[t]*inv;
    }
}

// ---- conv2 via MFMA: 3x3x3, 64->128, stride 2, pad 1; BN1+ReLU fused in staging ----
__global__ __launch_bounds__(256) void k_conv2(
        const u16* __restrict__ y1, const u16* __restrict__ wt2,
        float* __restrict__ stats, float* __restrict__ out) {
    const int ox = blockIdx.x, oyp = blockIdx.y, b = blockIdx.z;
    const int t = threadIdx.x;
    const int w = t >> 6, lane = t & 63;
    const int col = w >> 1, nh = w & 1, lo = lane & 15, hi = lane >> 4;

    __shared__ __align__(16) char pool[63488];
    u16* in2 = (u16*)pool;                // [2][52][64] bf16, slot^=((z>>1)&7)
    u16* w2s = (u16*)(pool + 13312);      // [24576] frag-linear
    float* red2 = (float*)(pool + 62464); // [256]
    red2[t] = 0.f;

    const float* sc1 = stats + SC1;
    const float* sh1 = stats + SH1;

    f32x4 acc[2][4];
    #pragma unroll
    for (int m=0;m<2;m++){ acc[m][0]=fzero(); acc[m][1]=fzero(); acc[m][2]=fzero(); acc[m][3]=fzero(); }

    const int oy = 2*oyp + col;
    for (int dxy = 0; dxy < 9; ++dxy) {
        int dx = dxy/3, dy = dxy - dx*3;
        int xi = 2*ox + dx - 1;
        bool okx = (xi >= 0) && (xi < GD);
        __syncthreads();
        for (int i = t; i < 832; i += 256) {
            int c = (i >= 416) ? 1 : 0;
            int cc = i - c*416;
            int z = cc >> 3, sl = cc & 7;
            int oyc = 2*oyp + c;
            int yi = 2*oyc + dy - 1;
            bool ok = okx && (oyc < 25) && (yi >= 0) && (yi < GD) && (z >= 1) && (z <= 50);
            uint4 vv = make_uint4(0u,0u,0u,0u);
            if (ok) vv = *(const uint4*)(y1 + (size_t)((b*GD + xi)*GD + yi)*3200 + cc*8 - 64);
            const u16* p = (const u16*)&vv;
            u16 d8[8];
            #pragma unroll
            for (int j=0;j<8;j++) {
                int ci = sl*8 + j;
                d8[j] = ok ? f2bf(fmaxf(bf2f(p[j])*sc1[ci] + sh1[ci], 0.f)) : (u16)0;
            }
            *(uint4*)(in2 + (c*52 + z)*64 + ((sl ^ ((z>>1) & 7)) << 3)) = *(uint4*)d8;
        }
        {
            const u16* wsrc = wt2 + dxy*24576;
            #pragma unroll
            for (int i2 = 0; i2 < 12; ++i2) {
                int i = t + i2*256;
                *(uint4*)(w2s + i*8) = *(const uint4*)(wsrc + i*8);
            }
        }
        __syncthreads();
        #pragma unroll
        for (int dz = 0; dz < 3; ++dz) {
            #pragma unroll
            for (int kc = 0; kc < 2; ++kc) {
                bf16x8 a[2], bb[4];
                #pragma unroll
                for (int mf = 0; mf < 2; ++mf) {
                    int z = 2*(mf*16 + lo) + dz; z = (z > 51) ? 51 : z;
                    a[mf] = *(const bf16x8*)(in2 + (col*52 + z)*64 + (((kc*4 + hi) ^ ((z>>1) & 7)) << 3));
                }
                #pragma unroll
                for (int nf = 0; nf < 4; ++nf)
                    bb[nf] = *(const bf16x8*)(w2s + (((dz*2 + kc)*4 + hi)*128 + (nh*4 + nf)*16 + lo)*8);
                #pragma unroll
                for (int mf = 0; mf < 2; ++mf) {
                    #pragma unroll
                    for (int nf = 0; nf < 4; ++nf)
                        acc[mf][nf] = __builtin_amdgcn_mfma_f32_16x16x32_bf16(a[mf], bb[nf], acc[mf][nf], 0, 0, 0);
                }
            }
        }
    }
    __syncthreads();
    float* trans = (float*)pool;      // [2][128][25] f32 = 25600 B
    if (oy < 25) {
        #pragma unroll
        for (int nf = 0; nf < 4; ++nf) {
            float s = 0.f, q = 0.f;
            int co = (nh*4 + nf)*16 + lo;
            #pragma unroll
            for (int mf = 0; mf < 2; ++mf) {
                #pragma unroll
                for (int r = 0; r < 4; ++r) {
                    int o = mf*16 + hi*4 + r;
                    if (o < 25) {
                        float vv = acc[mf][nf][r];
                        trans[(col*128 + co)*25 + o] = vv;
                        s += vv; q += vv*vv;
                    }
                }
            }
            atomicAdd(&red2[co], s);
            atomicAdd(&red2[128 + co], q);
        }
    }
    __syncthreads();
    if (t < 128) {
        atomicAdd(&stats[S2_SUM + t], red2[t]);
        atomicAdd(&stats[S2_SQ  + t], red2[128 + t]);
    }
    for (int i = t; i < 6400; i += 256) {
        int c = i / 3200; int r = i - c*3200;
        int co = r / 25;  int oz = r - co*25;
        int oyc = 2*oyp + c;
        if (oyc < 25)
            out[((size_t)(b*128 + co)*625 + ox*25 + oyc)*25 + oz] = trans[(c*128 + co)*25 + oz];
    }
}

// ---- BN2 + ReLU in place on d_out ----
__global__ void k_bnrelu2(float* __restrict__ out, const float* __restrict__ stats) {
    int idx = blockIdx.x*256 + threadIdx.x;
    if (idx >= 8000000) return;
    int co = (idx / 15625) & 127;
    float v = out[idx];
    out[idx] = fmaxf(v*stats[SC2 + co] + stats[SH2 + co], 0.f);
}

extern "C" void kernel_launch(void* const* d_in, const int* in_sizes, int n_in,
                              void* d_out, int out_size, void* d_ws, size_t ws_size,
                              hipStream_t stream) {
    const float* vf     = (const float*)d_in[0];
    const int*   coords = (const int*)  d_in[1];
    const float* W1 = (const float*)d_in[2];
    const float* b1 = (const float*)d_in[3];
    const float* W2 = (const float*)d_in[4];
    const float* b2 = (const float*)d_in[5];
    const float* W3 = (const float*)d_in[6];
    const float* b3 = (const float*)d_in[7];
    const float* k1 = (const float*)d_in[8];
    const float* g1 = (const float*)d_in[9];
    const float* be1= (const float*)d_in[10];
    const float* k2 = (const float*)d_in[11];
    const float* g2 = (const float*)d_in[12];
    const float* be2= (const float*)d_in[13];

    char* ws = (char*)d_ws;
    int*   owner = (int*)  (ws + OWNER_OFF);
    float* stats = (float*)(ws + STATS_OFF);
    u16*   wt1   = (u16*)  (ws + WT1_OFF);
    u16*   wt2   = (u16*)  (ws + WT2_OFF);
    u16*   vw2f  = (u16*)  (ws + VW2F_OFF);
    u16*   vw3f  = (u16*)  (ws + VW3F_OFF);
    u16*   grid  = (u16*)  (ws + GRID_OFF);
    u16*   y1    = (u16*)  (ws + Y1_OFF);
    u16*   zpad  = (u16*)  (ws + ZPAD_OFF);
    float* out   = (float*)d_out;

    hipMemsetAsync(owner, 0xFF, (size_t)NB*CELLS*4, stream);
    hipMemsetAsync(stats, 0, 768*4, stream);
    hipMemsetAsync(grid, 0, (size_t)NB*GD*GD*PZ*128*2, stream);
    hipMemsetAsync(zpad, 0, 13312, stream);

    k_wt_transform<<<864, 256, 0, stream>>>(k1, k2, W2, W3, wt1, wt2, vw2f, vw3f);
    k_owner<<<(NB*NVOX+255)/256, 256, 0, stream>>>(coords, owner);
    k_vfe<<<NB*NVOX/4, 256, 0, stream>>>(vf, coords, W1, b1, b2, b3, vw2f, vw3f, owner, grid);
    k_conv1<<<2600, 256, 0, stream>>>(grid, wt1, zpad, y1, stats);
    k_finalize<<<1, 64, 0, stream>>>(stats, g1, be1, 64, 500000.f, S1_SUM, SC1, SH1);
    k_conv2<<<dim3(25,13,NB), 256, 0, stream>>>(y1, wt2, stats, out);
    k_finalize<<<1, 128, 0, stream>>>(stats, g2, be2, 128, 62500.f, S2_SUM, SC2, SH2);
    k_bnrelu2<<<(8000000+255)/256, 256, 0, stream>>>(out, stats);
}

// Round 7
// 828.045 us; speedup vs baseline: 1.0243x; 1.0243x over previous
//
#include <hip/hip_runtime.h>

typedef unsigned short u16;
typedef unsigned int u32;
typedef __attribute__((ext_vector_type(8))) short bf16x8;
typedef __attribute__((ext_vector_type(4))) float f32x4;

#define NB 4
#define NVOX 8192
#define GD 50
#define PZ 52
#define CELLS 125000

// ---- workspace layout (bytes) ----
#define OWNER_OFF 0u            // int32[4*125000] = 2,000,000
#define STATS_OFF 2000000u      // f32[768]
#define WT1_OFF   2003072u      // bf16 27*64*128 frag-linear = 442,368
#define WT2_OFF   2445440u      // bf16 27*128*64 frag-linear = 442,368
#define VW2F_OFF  2887808u      // bf16 8*128*8  = 16,384 (W2^T frag-linear)
#define VW3F_OFF  2904192u      // bf16 16*128*8 = 32,768 (W3^T frag-linear)
#define GRID_OFF  2936960u      // bf16 4*50*50*52*128 = 133,120,000
#define Y1_OFF    136056960u    // bf16 4*50*50*50*64  =  64,000,000

#define S1_SUM 0
#define S1_SQ  64
#define SC1    128
#define SH1    192
#define S2_SUM 256
#define S2_SQ  384
#define SC2    512
#define SH2    640

__device__ __forceinline__ float bf2f(u16 v){ union{u32 u; float f;} x; x.u=((u32)v)<<16; return x.f; }
__device__ __forceinline__ u16 f2bf(float f){ union{u32 u; float f;} x; x.f=f; u32 r = x.u + 0x7fffu + ((x.u>>16)&1u); return (u16)(r>>16); }
__device__ __forceinline__ f32x4 fzero(){ f32x4 v; v[0]=0.f; v[1]=0.f; v[2]=0.f; v[3]=0.f; return v; }

// ---- weight re-layout ----
__global__ void k_wt_transform(const float* __restrict__ k1, const float* __restrict__ k2,
                               const float* __restrict__ W2, const float* __restrict__ W3,
                               u16* __restrict__ wt1, u16* __restrict__ wt2,
                               u16* __restrict__ vw2f, u16* __restrict__ vw3f) {
    int idx = blockIdx.x * 256 + threadIdx.x;
    if (idx < 221184) {
        {
            int j = idx & 7, co = (idx>>3)&63, kq = (idx>>9)&3, kc = (idx>>11)&3, s = idx>>13;
            int ci = kc*32 + kq*8 + j;
            wt1[idx] = f2bf(k1[(co*128 + ci)*27 + s]);
        }
        {
            int j = idx & 7, co = (idx>>3)&127, kq = (idx>>10)&3, kc = (idx>>12)&1, s = idx>>13;
            int ci = kc*32 + kq*8 + j;
            wt2[idx] = f2bf(k2[(co*64 + ci)*27 + s]);
        }
    }
    if (idx < 8192) {
        int j = idx & 7, n = (idx>>3)&127, q = idx>>10;
        vw2f[idx] = f2bf(W2[(q*8+j)*128 + n]);
    }
    if (idx < 16384) {
        int j = idx & 7, n = (idx>>3)&127, q = idx>>10;
        vw3f[idx] = f2bf(W3[(q*8+j)*128 + n]);
    }
}

// ---- duplicate resolution: last-write-wins == max n per cell ----
__global__ void k_owner(const int* __restrict__ coords, int* __restrict__ owner) {
    int v = blockIdx.x * 256 + threadIdx.x;
    if (v >= NB*NVOX) return;
    int b = v >> 13, n = v & (NVOX-1);
    int x = coords[v*3], y = coords[v*3+1], z = coords[v*3+2];
    atomicMax(&owner[b*CELLS + (x*GD + y)*GD + z], n);
}

// ---- VFE via MFMA: 4 voxels (128 points) per block, 4 waves ----
__global__ __launch_bounds__(256, 2) void k_vfe(
        const float* __restrict__ vf, const int* __restrict__ coords,
        const float* __restrict__ W1, const float* __restrict__ b1,
        const float* __restrict__ b2, const float* __restrict__ b3,
        const u16* __restrict__ vw2f, const u16* __restrict__ vw3f,
        const int* __restrict__ owner, u16* __restrict__ grid) {
    const int bid = blockIdx.x;
    const int t = threadIdx.x;
    const int w = t >> 6, lane = t & 63;
    const int lo = lane & 15, hi = lane >> 4;
    const int chgrp = w >> 1, pgrp = w & 1;

    __shared__ __align__(16) char pool[49152];
    u16* h1s = (u16*)pool;                 // [128][64] bf16 swizzled
    char* h2s = pool + 16384;              // [128][128] bf16 swizzled
    float* red = (float*)(pool + 16384);   // [4 vox][16 lo][128 ch] f32 (reuses h2s)

    bf16x8 wa2[2][4], wa3[4][4];
    #pragma unroll
    for (int kk = 0; kk < 2; ++kk)
        #pragma unroll
        for (int cf = 0; cf < 4; ++cf)
            wa2[kk][cf] = *(const bf16x8*)(vw2f + (((kk*4+hi)*128) + chgrp*64 + cf*16 + lo)*8);
    #pragma unroll
    for (int kk = 0; kk < 4; ++kk)
        #pragma unroll
        for (int cf = 0; cf < 4; ++cf)
            wa3[kk][cf] = *(const bf16x8*)(vw3f + (((kk*4+hi)*128) + chgrp*64 + cf*16 + lo)*8);
    f32x4 bb2[4];
    #pragma unroll
    for (int cf = 0; cf < 4; ++cf)
        bb2[cf] = *(const f32x4*)(b2 + chgrp*64 + cf*16 + hi*4);

    {
        const int pt = t & 127, C0 = (t >> 7) * 32;
        f32x4 xv0 = *(const f32x4*)(vf + (size_t)(bid*128 + pt)*8);
        f32x4 xv1 = *(const f32x4*)(vf + (size_t)(bid*128 + pt)*8 + 4);
        float x[8] = {xv0[0],xv0[1],xv0[2],xv0[3],xv1[0],xv1[1],xv1[2],xv1[3]};
        float h[32];
        #pragma unroll
        for (int c = 0; c < 32; ++c) h[c] = b1[C0 + c];
        #pragma unroll
        for (int k = 0; k < 8; ++k) {
            float xk = x[k];
            #pragma unroll
            for (int c = 0; c < 32; ++c) h[c] += xk * W1[k*64 + C0 + c];
        }
        #pragma unroll
        for (int c8 = 0; c8 < 4; ++c8) {
            u16 d8[8];
            #pragma unroll
            for (int j = 0; j < 8; ++j) d8[j] = f2bf(fmaxf(h[c8*8 + j], 0.f));
            int slot = ((C0 >> 3) + c8) ^ (pt & 7);
            *(uint4*)(h1s + pt*64 + slot*8) = *(uint4*)d8;
        }
    }
    __syncthreads();

    f32x4 acc2[4][4];
    #pragma unroll
    for (int cf = 0; cf < 4; ++cf)
        #pragma unroll
        for (int pf = 0; pf < 4; ++pf) acc2[cf][pf] = fzero();
    #pragma unroll
    for (int kk = 0; kk < 2; ++kk) {
        bf16x8 bh[4];
        #pragma unroll
        for (int pf = 0; pf < 4; ++pf) {
            int pt = pgrp*64 + pf*16 + lo;
            bh[pf] = *(const bf16x8*)(h1s + pt*64 + (((kk*4+hi) ^ (pt&7)) << 3));
        }
        #pragma unroll
        for (int cf = 0; cf < 4; ++cf)
            #pragma unroll
            for (int pf = 0; pf < 4; ++pf)
                acc2[cf][pf] = __builtin_amdgcn_mfma_f32_16x16x32_bf16(wa2[kk][cf], bh[pf], acc2[cf][pf], 0, 0, 0);
    }
    #pragma unroll
    for (int cf = 0; cf < 4; ++cf) {
        #pragma unroll
        for (int pf = 0; pf < 4; ++pf) {
            int pt = pgrp*64 + pf*16 + lo;
            float v0 = fmaxf(acc2[cf][pf][0] + bb2[cf][0], 0.f);
            float v1 = fmaxf(acc2[cf][pf][1] + bb2[cf][1], 0.f);
            float v2 = fmaxf(acc2[cf][pf][2] + bb2[cf][2], 0.f);
            float v3 = fmaxf(acc2[cf][pf][3] + bb2[cf][3], 0.f);
            uint2 d;
            d.x = (u32)f2bf(v0) | ((u32)f2bf(v1) << 16);
            d.y = (u32)f2bf(v2) | ((u32)f2bf(v3) << 16);
            int s = (chgrp*8 + cf*2 + (hi>>1)) ^ (pt & 15);
            *(uint2*)(h2s + pt*256 + s*16 + (hi&1)*8) = d;
        }
    }
    __syncthreads();

    f32x4 acc3[4][4];
    #pragma unroll
    for (int cf = 0; cf < 4; ++cf)
        #pragma unroll
        for (int pf = 0; pf < 4; ++pf) acc3[cf][pf] = fzero();
    #pragma unroll
    for (int kk = 0; kk < 4; ++kk) {
        bf16x8 bh[4];
        #pragma unroll
        for (int pf = 0; pf < 4; ++pf) {
            int pt = pgrp*64 + pf*16 + lo;
            bh[pf] = *(const bf16x8*)(h2s + pt*256 + (((kk*4+hi) ^ (pt&15)) << 4));
        }
        #pragma unroll
        for (int cf = 0; cf < 4; ++cf)
            #pragma unroll
            for (int pf = 0; pf < 4; ++pf)
                acc3[cf][pf] = __builtin_amdgcn_mfma_f32_16x16x32_bf16(wa3[kk][cf], bh[pf], acc3[cf][pf], 0, 0, 0);
    }
    __syncthreads();

    #pragma unroll
    for (int vox01 = 0; vox01 < 2; ++vox01) {
        int vv = pgrp*2 + vox01;
        #pragma unroll
        for (int cf = 0; cf < 4; ++cf) {
            f32x4 mx;
            #pragma unroll
            for (int r = 0; r < 4; ++r)
                mx[r] = fmaxf(acc3[cf][vox01*2][r], acc3[cf][vox01*2+1][r]);
            int s4 = (cf*4 + hi) ^ lo;
            *(f32x4*)(red + vv*2048 + lo*128 + chgrp*64 + s4*4) = mx;
        }
    }
    __syncthreads();

    #pragma unroll
    for (int half = 0; half < 2; ++half) {
        int vv = (t >> 7) + half*2;
        int ch = t & 127;
        int cq = (ch & 63) >> 2, e = ch & 3, cg = ch >> 6;
        float m = -3.0e38f;
        #pragma unroll
        for (int lo2 = 0; lo2 < 16; ++lo2)
            m = fmaxf(m, red[vv*2048 + lo2*128 + cg*64 + ((cq ^ lo2) << 2) + e]);
        int gv = bid*4 + vv;
        int b = gv >> 13, n = gv & (NVOX-1);
        int x = coords[gv*3], y = coords[gv*3+1], z = coords[gv*3+2];
        if (owner[b*CELLS + (x*GD + y)*GD + z] == n) {
            size_t gi = ((((size_t)b*GD + x)*GD + y)*PZ + (z+1))*128 + ch;
            grid[gi] = f2bf(m + b3[ch]);
        }
    }
}

// ---- pipelined-loop macros for conv1 ----
#define LOADB(dst, sv, kc0) { \
    _Pragma("unroll") \
    for (int kk = 0; kk < 2; ++kk) { \
        _Pragma("unroll") \
        for (int nf = 0; nf < 4; ++nf) \
            dst[kk][nf] = *(const bf16x8*)(wt1 + (size_t)((((sv)*4 + (kc0) + kk)*4 + hi)*512) + (nf*16 + lo)*8); \
    } }

#define READA(dst, dzv, kcv) { \
    _Pragma("unroll") \
    for (int mf = 0; mf < 4; ++mf) { \
        int z = mf*16 + lo + (dzv); z = (z > 51) ? 51 : z; \
        dst[mf] = *(const bf16x8*)(in_s + col*6656 + z*128 + ((((kcv)*4 + hi) ^ (z & 15)) << 3)); \
    } }

#define DOMFMA(av, bv) { \
    _Pragma("unroll") \
    for (int mf = 0; mf < 4; ++mf) { \
        _Pragma("unroll") \
        for (int nf = 0; nf < 4; ++nf) \
            acc[mf][nf] = __builtin_amdgcn_mfma_f32_16x16x32_bf16(av[mf], bv[nf], acc[mf][nf], 0, 0, 0); \
    } }

// ---- conv1 via MFMA: 3x3x3, 128->64, stride 1, pad 1 ----
// Block = 4 oy columns (1 per wave), wave tile 64z x 64co. A from LDS (staged
// per dx, 6 columns). B streamed from L2 into registers with an explicit
// 12-step software pipeline per (dx,dy): B 2 steps ahead (~620cyc >= L2 lat),
// A 1 step ahead (>= LDS lat). Named live buffers keep the dbuf in VGPRs.
__global__ __launch_bounds__(256, 2) void k_conv1(
        const u16* __restrict__ grid, const u16* __restrict__ wt1,
        u16* __restrict__ y1, float* __restrict__ stats) {
    const int ox = blockIdx.x, oyp = blockIdx.y, b = blockIdx.z;
    const int t = threadIdx.x;
    const int w = t >> 6, lane = t & 63;
    const int lo = lane & 15, hi = lane >> 4;
    const int oy = oyp*4 + w;

    __shared__ __align__(16) u16 in_s[6*52*128];   // 79,872 B, slot^=(z&15)
    __shared__ float red[128];
    if (t < 128) red[t] = 0.f;

    f32x4 acc[4][4];
    #pragma unroll
    for (int mf = 0; mf < 4; ++mf)
        #pragma unroll
        for (int nf = 0; nf < 4; ++nf) acc[mf][nf] = fzero();

    for (int dx = 0; dx < 3; ++dx) {
        int xi = ox + dx - 1;
        bool okx = (xi >= 0) && (xi < GD);
        __syncthreads();
        // stage 6 input columns yi = 4*oyp-1 .. 4*oyp+4 (sync, VGPR path)
        #pragma unroll
        for (int c = 0; c < 6; ++c) {
            int yi = oyp*4 - 1 + c;
            bool ok = okx && (yi >= 0) && (yi < GD);
            const u16* src = grid + ((size_t)(b*GD + xi)*GD + yi)*(size_t)(PZ*128);
            for (int i = t; i < 832; i += 256) {
                int z = i >> 4, sl = i & 15;
                uint4 v = make_uint4(0u,0u,0u,0u);
                if (ok) v = *(const uint4*)(src + i*8);
                *(uint4*)(in_s + c*6656 + z*128 + ((sl ^ (z & 15)) << 3)) = v;
            }
        }
        __syncthreads();
        #pragma unroll
        for (int dy = 0; dy < 3; ++dy) {
            const int col = w + dy;
            const int s0 = (dx*3 + dy)*3;
            bf16x8 bbA[2][4], bbB[2][4], aP[4], aQ[4];
            // prologue
            LOADB(bbA, s0, 0);
            READA(aP, 0, 0);
            LOADB(bbB, s0, 2);          // for steps 2,3
            READA(aQ, 0, 1);            // step 1's A
            // 12 steps: step k uses (dz=k/4, kc=k%4)
            DOMFMA(aP, bbA[0]);         // step 0
            READA(aP, 0, 2);
            DOMFMA(aQ, bbA[1]);         // step 1
            LOADB(bbA, s0+1, 0);        // for steps 4,5
            READA(aQ, 0, 3);
            DOMFMA(aP, bbB[0]);         // step 2
            READA(aP, 1, 0);
            DOMFMA(aQ, bbB[1]);         // step 3
            LOADB(bbB, s0+1, 2);        // for steps 6,7
            READA(aQ, 1, 1);
            DOMFMA(aP, bbA[0]);         // step 4
            READA(aP, 1, 2);
            DOMFMA(aQ, bbA[1]);         // step 5
            LOADB(bbA, s0+2, 0);        // for steps 8,9
            READA(aQ, 1, 3);
            DOMFMA(aP, bbB[0]);         // step 6
            READA(aP, 2, 0);
            DOMFMA(aQ, bbB[1]);         // step 7
            LOADB(bbB, s0+2, 2);        // for steps 10,11
            READA(aQ, 2, 1);
            DOMFMA(aP, bbA[0]);         // step 8
            READA(aP, 2, 2);
            DOMFMA(aQ, bbA[1]);         // step 9
            READA(aQ, 2, 3);
            DOMFMA(aP, bbB[0]);         // step 10
            DOMFMA(aQ, bbB[1]);         // step 11
        }
    }

    // epilogue: store y1 + stats partials
    if (oy < GD) {
        const size_t colbase = ((size_t)(b*GD + ox)*GD + oy)*50;
        float s[4] = {0.f,0.f,0.f,0.f}, q[4] = {0.f,0.f,0.f,0.f};
        #pragma unroll
        for (int mf = 0; mf < 4; ++mf) {
            #pragma unroll
            for (int r = 0; r < 4; ++r) {
                int o = mf*16 + hi*4 + r;
                if (o < 50) {
                    #pragma unroll
                    for (int nf = 0; nf < 4; ++nf) {
                        float v = acc[mf][nf][r];
                        y1[(colbase + o)*64 + nf*16 + lo] = f2bf(v);
                        s[nf] += v; q[nf] += v*v;
                    }
                }
            }
        }
        #pragma unroll
        for (int nf = 0; nf < 4; ++nf) {
            atomicAdd(&red[nf*16 + lo], s[nf]);
            atomicAdd(&red[64 + nf*16 + lo], q[nf]);
        }
    }
    __syncthreads();
    if (t < 64) {
        atomicAdd(&stats[S1_SUM + t], red[t]);
        atomicAdd(&stats[S1_SQ  + t], red[64 + t]);
    }
}

// ---- BN finalize ----
__global__ void k_finalize(float* __restrict__ stats, const float* __restrict__ g,
                           const float* __restrict__ be, int C, float cnt,
                           int st_off, int sc_off, int sh_off) {
    int t = threadIdx.x;
    if (t < C) {
        float mean = stats[st_off + t] / cnt;
        float var  = stats[st_off + C + t] / cnt - mean*mean;
        float inv  = rsqrtf(var + 1e-5f);
        stats[sc_off + t] = g[t]*inv;
        stats[sh_off + t] = be[t] - mean*g[t]*inv;
    }
}

// ---- conv2 via MFMA: 3x3x3, 64->128, stride 2, pad 1; BN1+ReLU fused in staging ----
__global__ __launch_bounds__(256) void k_conv2(
        const u16* __restrict__ y1, const u16* __restrict__ wt2,
        float* __restrict__ stats, float* __restrict__ out) {
    const int ox = blockIdx.x, oyp = blockIdx.y, b = blockIdx.z;
    const int t = threadIdx.x;
    const int w = t >> 6, lane = t & 63;
    const int col = w >> 1, nh = w & 1, lo = lane & 15, hi = lane >> 4;

    __shared__ __align__(16) char pool[63488];
    u16* in2 = (u16*)pool;                // [2][52][64] bf16, slot^=((z>>1)&7)
    u16* w2s = (u16*)(pool + 13312);      // [24576] frag-linear
    float* red2 = (float*)(pool + 62464); // [256]
    red2[t] = 0.f;

    const float* sc1 = stats + SC1;
    const float* sh1 = stats + SH1;

    f32x4 acc[2][4];
    #pragma unroll
    for (int m=0;m<2;m++){ acc[m][0]=fzero(); acc[m][1]=fzero(); acc[m][2]=fzero(); acc[m][3]=fzero(); }

    const int oy = 2*oyp + col;
    for (int dxy = 0; dxy < 9; ++dxy) {
        int dx = dxy/3, dy = dxy - dx*3;
        int xi = 2*ox + dx - 1;
        bool okx = (xi >= 0) && (xi < GD);
        __syncthreads();
        for (int i = t; i < 832; i += 256) {
            int c = (i >= 416) ? 1 : 0;
            int cc = i - c*416;
            int z = cc >> 3, sl = cc & 7;
            int oyc = 2*oyp + c;
            int yi = 2*oyc + dy - 1;
            bool ok = okx && (oyc < 25) && (yi >= 0) && (yi < GD) && (z >= 1) && (z <= 50);
            uint4 vv = make_uint4(0u,0u,0u,0u);
            if (ok) vv = *(const uint4*)(y1 + (size_t)((b*GD + xi)*GD + yi)*3200 + cc*8 - 64);
            const u16* p = (const u16*)&vv;
            u16 d8[8];
            #pragma unroll
            for (int j=0;j<8;j++) {
                int ci = sl*8 + j;
                d8[j] = ok ? f2bf(fmaxf(bf2f(p[j])*sc1[ci] + sh1[ci], 0.f)) : (u16)0;
            }
            *(uint4*)(in2 + (c*52 + z)*64 + ((sl ^ ((z>>1) & 7)) << 3)) = *(uint4*)d8;
        }
        {
            const u16* wsrc = wt2 + dxy*24576;
            #pragma unroll
            for (int i2 = 0; i2 < 12; ++i2) {
                int i = t + i2*256;
                *(uint4*)(w2s + i*8) = *(const uint4*)(wsrc + i*8);
            }
        }
        __syncthreads();
        #pragma unroll
        for (int dz = 0; dz < 3; ++dz) {
            #pragma unroll
            for (int kc = 0; kc < 2; ++kc) {
                bf16x8 a[2], bb[4];
                #pragma unroll
                for (int mf = 0; mf < 2; ++mf) {
                    int z = 2*(mf*16 + lo) + dz; z = (z > 51) ? 51 : z;
                    a[mf] = *(const bf16x8*)(in2 + (col*52 + z)*64 + (((kc*4 + hi) ^ ((z>>1) & 7)) << 3));
                }
                #pragma unroll
                for (int nf = 0; nf < 4; ++nf)
                    bb[nf] = *(const bf16x8*)(w2s + (((dz*2 + kc)*4 + hi)*128 + (nh*4 + nf)*16 + lo)*8);
                #pragma unroll
                for (int mf = 0; mf < 2; ++mf) {
                    #pragma unroll
                    for (int nf = 0; nf < 4; ++nf)
                        acc[mf][nf] = __builtin_amdgcn_mfma_f32_16x16x32_bf16(a[mf], bb[nf], acc[mf][nf], 0, 0, 0);
                }
            }
        }
    }
    __syncthreads();
    float* trans = (float*)pool;      // [2][128][25] f32 = 25600 B
    if (oy < 25) {
        #pragma unroll
        for (int nf = 0; nf < 4; ++nf) {
            float s = 0.f, q = 0.f;
            int co = (nh*4 + nf)*16 + lo;
            #pragma unroll
            for (int mf = 0; mf < 2; ++mf) {
                #pragma unroll
                for (int r = 0; r < 4; ++r) {
                    int o = mf*16 + hi*4 + r;
                    if (o < 25) {
                        float vv = acc[mf][nf][r];
                        trans[(col*128 + co)*25 + o] = vv;
                        s += vv; q += vv*vv;
                    }
                }
            }
            atomicAdd(&red2[co], s);
            atomicAdd(&red2[128 + co], q);
        }
    }
    __syncthreads();
    if (t < 128) {
        atomicAdd(&stats[S2_SUM + t], red2[t]);
        atomicAdd(&stats[S2_SQ  + t], red2[128 + t]);
    }
    for (int i = t; i < 6400; i += 256) {
        int c = i / 3200; int r = i - c*3200;
        int co = r / 25;  int oz = r - co*25;
        int oyc = 2*oyp + c;
        if (oyc < 25)
            out[((size_t)(b*128 + co)*625 + ox*25 + oyc)*25 + oz] = trans[(c*128 + co)*25 + oz];
    }
}

// ---- BN2 + ReLU in place on d_out ----
__global__ void k_bnrelu2(float* __restrict__ out, const float* __restrict__ stats) {
    int idx = blockIdx.x*256 + threadIdx.x;
    if (idx >= 8000000) return;
    int co = (idx / 15625) & 127;
    float v = out[idx];
    out[idx] = fmaxf(v*stats[SC2 + co] + stats[SH2 + co], 0.f);
}

extern "C" void kernel_launch(void* const* d_in, const int* in_sizes, int n_in,
                              void* d_out, int out_size, void* d_ws, size_t ws_size,
                              hipStream_t stream) {
    const float* vf     = (const float*)d_in[0];
    const int*   coords = (const int*)  d_in[1];
    const float* W1 = (const float*)d_in[2];
    const float* b1 = (const float*)d_in[3];
    const float* W2 = (const float*)d_in[4];
    const float* b2 = (const float*)d_in[5];
    const float* W3 = (const float*)d_in[6];
    const float* b3 = (const float*)d_in[7];
    const float* k1 = (const float*)d_in[8];
    const float* g1 = (const float*)d_in[9];
    const float* be1= (const float*)d_in[10];
    const float* k2 = (const float*)d_in[11];
    const float* g2 = (const float*)d_in[12];
    const float* be2= (const float*)d_in[13];

    char* ws = (char*)d_ws;
    int*   owner = (int*)  (ws + OWNER_OFF);
    float* stats = (float*)(ws + STATS_OFF);
    u16*   wt1   = (u16*)  (ws + WT1_OFF);
    u16*   wt2   = (u16*)  (ws + WT2_OFF);
    u16*   vw2f  = (u16*)  (ws + VW2F_OFF);
    u16*   vw3f  = (u16*)  (ws + VW3F_OFF);
    u16*   grid  = (u16*)  (ws + GRID_OFF);
    u16*   y1    = (u16*)  (ws + Y1_OFF);
    float* out   = (float*)d_out;

    hipMemsetAsync(owner, 0xFF, (size_t)NB*CELLS*4, stream);
    hipMemsetAsync(stats, 0, 768*4, stream);
    hipMemsetAsync(grid, 0, (size_t)NB*GD*GD*PZ*128*2, stream);

    k_wt_transform<<<864, 256, 0, stream>>>(k1, k2, W2, W3, wt1, wt2, vw2f, vw3f);
    k_owner<<<(NB*NVOX+255)/256, 256, 0, stream>>>(coords, owner);
    k_vfe<<<NB*NVOX/4, 256, 0, stream>>>(vf, coords, W1, b1, b2, b3, vw2f, vw3f, owner, grid);
    k_conv1<<<dim3(GD,13,NB), 256, 0, stream>>>(grid, wt1, y1, stats);
    k_finalize<<<1, 64, 0, stream>>>(stats, g1, be1, 64, 500000.f, S1_SUM, SC1, SH1);
    k_conv2<<<dim3(25,13,NB), 256, 0, stream>>>(y1, wt2, stats, out);
    k_finalize<<<1, 128, 0, stream>>>(stats, g2, be2, 128, 62500.f, S2_SUM, SC2, SH2);
    k_bnrelu2<<<(8000000+255)/256, 256, 0, stream>>>(out, stats);
}

// Round 8
// 785.970 us; speedup vs baseline: 1.0791x; 1.0535x over previous
//
#include <hip/hip_runtime.h>

typedef unsigned short u16;
typedef unsigned int u32;
typedef __attribute__((ext_vector_type(8))) short bf16x8;
typedef __attribute__((ext_vector_type(4))) float f32x4;

#define NB 4
#define NVOX 8192
#define GD 50
#define PZ 52
#define CELLS 125000

// ---- workspace layout (bytes) ----
#define OWNER_OFF 0u            // int32[4*125000] = 2,000,000
#define STATS_OFF 2000000u      // f32[768]
#define WT1_OFF   2003072u      // bf16 27*64*128 frag-linear = 442,368
#define WT2_OFF   2445440u      // bf16 27*128*64 frag-linear = 442,368
#define VW2F_OFF  2887808u      // bf16 8*128*8  = 16,384 (W2^T frag-linear)
#define VW3F_OFF  2904192u      // bf16 16*128*8 = 32,768 (W3^T frag-linear)
#define GRID_OFF  2936960u      // bf16 4*50*50*52*128 = 133,120,000
#define Y1_OFF    136056960u    // bf16 4*50*50*50*64  =  64,000,000

#define S1_SUM 0
#define S1_SQ  64
#define SC1    128
#define SH1    192
#define S2_SUM 256
#define S2_SQ  384
#define SC2    512
#define SH2    640

__device__ __forceinline__ float bf2f(u16 v){ union{u32 u; float f;} x; x.u=((u32)v)<<16; return x.f; }
__device__ __forceinline__ u16 f2bf(float f){ union{u32 u; float f;} x; x.f=f; u32 r = x.u + 0x7fffu + ((x.u>>16)&1u); return (u16)(r>>16); }
__device__ __forceinline__ f32x4 fzero(){ f32x4 v; v[0]=0.f; v[1]=0.f; v[2]=0.f; v[3]=0.f; return v; }

// ---- weight re-layout ----
__global__ void k_wt_transform(const float* __restrict__ k1, const float* __restrict__ k2,
                               const float* __restrict__ W2, const float* __restrict__ W3,
                               u16* __restrict__ wt1, u16* __restrict__ wt2,
                               u16* __restrict__ vw2f, u16* __restrict__ vw3f) {
    int idx = blockIdx.x * 256 + threadIdx.x;
    if (idx < 221184) {
        {
            int j = idx & 7, co = (idx>>3)&63, kq = (idx>>9)&3, kc = (idx>>11)&3, s = idx>>13;
            int ci = kc*32 + kq*8 + j;
            wt1[idx] = f2bf(k1[(co*128 + ci)*27 + s]);
        }
        {
            int j = idx & 7, co = (idx>>3)&127, kq = (idx>>10)&3, kc = (idx>>12)&1, s = idx>>13;
            int ci = kc*32 + kq*8 + j;
            wt2[idx] = f2bf(k2[(co*64 + ci)*27 + s]);
        }
    }
    if (idx < 8192) {
        int j = idx & 7, n = (idx>>3)&127, q = idx>>10;
        vw2f[idx] = f2bf(W2[(q*8+j)*128 + n]);
    }
    if (idx < 16384) {
        int j = idx & 7, n = (idx>>3)&127, q = idx>>10;
        vw3f[idx] = f2bf(W3[(q*8+j)*128 + n]);
    }
}

// ---- duplicate resolution: last-write-wins == max n per cell ----
__global__ void k_owner(const int* __restrict__ coords, int* __restrict__ owner) {
    int v = blockIdx.x * 256 + threadIdx.x;
    if (v >= NB*NVOX) return;
    int b = v >> 13, n = v & (NVOX-1);
    int x = coords[v*3], y = coords[v*3+1], z = coords[v*3+2];
    atomicMax(&owner[b*CELLS + (x*GD + y)*GD + z], n);
}

// ---- VFE via MFMA: 4 voxels (128 points) per block, 4 waves ----
__global__ __launch_bounds__(256, 2) void k_vfe(
        const float* __restrict__ vf, const int* __restrict__ coords,
        const float* __restrict__ W1, const float* __restrict__ b1,
        const float* __restrict__ b2, const float* __restrict__ b3,
        const u16* __restrict__ vw2f, const u16* __restrict__ vw3f,
        const int* __restrict__ owner, u16* __restrict__ grid) {
    const int bid = blockIdx.x;
    const int t = threadIdx.x;
    const int w = t >> 6, lane = t & 63;
    const int lo = lane & 15, hi = lane >> 4;
    const int chgrp = w >> 1, pgrp = w & 1;

    __shared__ __align__(16) char pool[49152];
    u16* h1s = (u16*)pool;                 // [128][64] bf16 swizzled
    char* h2s = pool + 16384;              // [128][128] bf16 swizzled
    float* red = (float*)(pool + 16384);   // [4 vox][16 lo][128 ch] f32 (reuses h2s)

    bf16x8 wa2[2][4], wa3[4][4];
    #pragma unroll
    for (int kk = 0; kk < 2; ++kk)
        #pragma unroll
        for (int cf = 0; cf < 4; ++cf)
            wa2[kk][cf] = *(const bf16x8*)(vw2f + (((kk*4+hi)*128) + chgrp*64 + cf*16 + lo)*8);
    #pragma unroll
    for (int kk = 0; kk < 4; ++kk)
        #pragma unroll
        for (int cf = 0; cf < 4; ++cf)
            wa3[kk][cf] = *(const bf16x8*)(vw3f + (((kk*4+hi)*128) + chgrp*64 + cf*16 + lo)*8);
    f32x4 bb2[4];
    #pragma unroll
    for (int cf = 0; cf < 4; ++cf)
        bb2[cf] = *(const f32x4*)(b2 + chgrp*64 + cf*16 + hi*4);

    {
        const int pt = t & 127, C0 = (t >> 7) * 32;
        f32x4 xv0 = *(const f32x4*)(vf + (size_t)(bid*128 + pt)*8);
        f32x4 xv1 = *(const f32x4*)(vf + (size_t)(bid*128 + pt)*8 + 4);
        float x[8] = {xv0[0],xv0[1],xv0[2],xv0[3],xv1[0],xv1[1],xv1[2],xv1[3]};
        float h[32];
        #pragma unroll
        for (int c = 0; c < 32; ++c) h[c] = b1[C0 + c];
        #pragma unroll
        for (int k = 0; k < 8; ++k) {
            float xk = x[k];
            #pragma unroll
            for (int c = 0; c < 32; ++c) h[c] += xk * W1[k*64 + C0 + c];
        }
        #pragma unroll
        for (int c8 = 0; c8 < 4; ++c8) {
            u16 d8[8];
            #pragma unroll
            for (int j = 0; j < 8; ++j) d8[j] = f2bf(fmaxf(h[c8*8 + j], 0.f));
            int slot = ((C0 >> 3) + c8) ^ (pt & 7);
            *(uint4*)(h1s + pt*64 + slot*8) = *(uint4*)d8;
        }
    }
    __syncthreads();

    f32x4 acc2[4][4];
    #pragma unroll
    for (int cf = 0; cf < 4; ++cf)
        #pragma unroll
        for (int pf = 0; pf < 4; ++pf) acc2[cf][pf] = fzero();
    #pragma unroll
    for (int kk = 0; kk < 2; ++kk) {
        bf16x8 bh[4];
        #pragma unroll
        for (int pf = 0; pf < 4; ++pf) {
            int pt = pgrp*64 + pf*16 + lo;
            bh[pf] = *(const bf16x8*)(h1s + pt*64 + (((kk*4+hi) ^ (pt&7)) << 3));
        }
        #pragma unroll
        for (int cf = 0; cf < 4; ++cf)
            #pragma unroll
            for (int pf = 0; pf < 4; ++pf)
                acc2[cf][pf] = __builtin_amdgcn_mfma_f32_16x16x32_bf16(wa2[kk][cf], bh[pf], acc2[cf][pf], 0, 0, 0);
    }
    #pragma unroll
    for (int cf = 0; cf < 4; ++cf) {
        #pragma unroll
        for (int pf = 0; pf < 4; ++pf) {
            int pt = pgrp*64 + pf*16 + lo;
            float v0 = fmaxf(acc2[cf][pf][0] + bb2[cf][0], 0.f);
            float v1 = fmaxf(acc2[cf][pf][1] + bb2[cf][1], 0.f);
            float v2 = fmaxf(acc2[cf][pf][2] + bb2[cf][2], 0.f);
            float v3 = fmaxf(acc2[cf][pf][3] + bb2[cf][3], 0.f);
            uint2 d;
            d.x = (u32)f2bf(v0) | ((u32)f2bf(v1) << 16);
            d.y = (u32)f2bf(v2) | ((u32)f2bf(v3) << 16);
            int s = (chgrp*8 + cf*2 + (hi>>1)) ^ (pt & 15);
            *(uint2*)(h2s + pt*256 + s*16 + (hi&1)*8) = d;
        }
    }
    __syncthreads();

    f32x4 acc3[4][4];
    #pragma unroll
    for (int cf = 0; cf < 4; ++cf)
        #pragma unroll
        for (int pf = 0; pf < 4; ++pf) acc3[cf][pf] = fzero();
    #pragma unroll
    for (int kk = 0; kk < 4; ++kk) {
        bf16x8 bh[4];
        #pragma unroll
        for (int pf = 0; pf < 4; ++pf) {
            int pt = pgrp*64 + pf*16 + lo;
            bh[pf] = *(const bf16x8*)(h2s + pt*256 + (((kk*4+hi) ^ (pt&15)) << 4));
        }
        #pragma unroll
        for (int cf = 0; cf < 4; ++cf)
            #pragma unroll
            for (int pf = 0; pf < 4; ++pf)
                acc3[cf][pf] = __builtin_amdgcn_mfma_f32_16x16x32_bf16(wa3[kk][cf], bh[pf], acc3[cf][pf], 0, 0, 0);
    }
    __syncthreads();

    #pragma unroll
    for (int vox01 = 0; vox01 < 2; ++vox01) {
        int vv = pgrp*2 + vox01;
        #pragma unroll
        for (int cf = 0; cf < 4; ++cf) {
            f32x4 mx;
            #pragma unroll
            for (int r = 0; r < 4; ++r)
                mx[r] = fmaxf(acc3[cf][vox01*2][r], acc3[cf][vox01*2+1][r]);
            int s4 = (cf*4 + hi) ^ lo;
            *(f32x4*)(red + vv*2048 + lo*128 + chgrp*64 + s4*4) = mx;
        }
    }
    __syncthreads();

    #pragma unroll
    for (int half = 0; half < 2; ++half) {
        int vv = (t >> 7) + half*2;
        int ch = t & 127;
        int cq = (ch & 63) >> 2, e = ch & 3, cg = ch >> 6;
        float m = -3.0e38f;
        #pragma unroll
        for (int lo2 = 0; lo2 < 16; ++lo2)
            m = fmaxf(m, red[vv*2048 + lo2*128 + cg*64 + ((cq ^ lo2) << 2) + e]);
        int gv = bid*4 + vv;
        int b = gv >> 13, n = gv & (NVOX-1);
        int x = coords[gv*3], y = coords[gv*3+1], z = coords[gv*3+2];
        if (owner[b*CELLS + (x*GD + y)*GD + z] == n) {
            size_t gi = ((((size_t)b*GD + x)*GD + y)*PZ + (z+1))*128 + ch;
            grid[gi] = f2bf(m + b3[ch]);
        }
    }
}

// ---- pipelined-loop macros for conv1 (M=32 half-z tile) ----
#define LOADB(dst, sv, kc0) { \
    _Pragma("unroll") \
    for (int kk = 0; kk < 2; ++kk) { \
        _Pragma("unroll") \
        for (int nf = 0; nf < 4; ++nf) \
            dst[kk][nf] = *(const bf16x8*)(wt1 + (size_t)((((sv)*4 + (kc0) + kk)*4 + hi)*512) + (nf*16 + lo)*8); \
    } }

#define READA(dst, dzv, kcv) { \
    _Pragma("unroll") \
    for (int mf = 0; mf < 2; ++mf) { \
        int zl = mf*16 + lo + (dzv); zl = (zl > 26) ? 26 : zl; \
        dst[mf] = *(const bf16x8*)(in_s + col*3456 + zl*128 + ((((kcv)*4 + hi) ^ (zl & 15)) << 3)); \
    } }

#define DOMFMA(av, bv) { \
    _Pragma("unroll") \
    for (int mf = 0; mf < 2; ++mf) { \
        _Pragma("unroll") \
        for (int nf = 0; nf < 4; ++nf) \
            acc[mf][nf] = __builtin_amdgcn_mfma_f32_16x16x32_bf16(av[mf], bv[nf], acc[mf][nf], 0, 0, 0); \
    } }

// ---- conv1 via MFMA: 3x3x3, 128->64, stride 1, pad 1 ----
// Block = 4 oy columns x HALF the z range (25 outputs): wave tile 32z x 64co.
// in_s = 6 cols x 27 z x 128 ci = 41.5KB -> 3 blocks/CU (12 waves, 3/SIMD) for
// latency hiding (the r5-r7 plateau at 2 waves/SIMD was latency-bound).
// B streamed from L2 into regs, 2-step lookahead; A 1 step ahead.
__global__ __launch_bounds__(256, 3) void k_conv1(
        const u16* __restrict__ grid, const u16* __restrict__ wt1,
        u16* __restrict__ y1, float* __restrict__ stats) {
    const int ox = blockIdx.x, oyp = blockIdx.y;
    const int b = blockIdx.z >> 1, h = blockIdx.z & 1;
    const int t = threadIdx.x;
    const int w = t >> 6, lane = t & 63;
    const int lo = lane & 15, hi = lane >> 4;
    const int oy = oyp*4 + w;

    __shared__ __align__(16) u16 in_s[6*27*128];   // 41,472 B, slot^=(z&15)
    __shared__ float red[128];
    if (t < 128) red[t] = 0.f;

    f32x4 acc[2][4];
    #pragma unroll
    for (int mf = 0; mf < 2; ++mf)
        #pragma unroll
        for (int nf = 0; nf < 4; ++nf) acc[mf][nf] = fzero();

    for (int dx = 0; dx < 3; ++dx) {
        int xi = ox + dx - 1;
        bool okx = (xi >= 0) && (xi < GD);
        __syncthreads();
        // stage 6 input columns yi = 4*oyp-1 .. +4, z rows h*25 .. h*25+26
        #pragma unroll
        for (int c = 0; c < 6; ++c) {
            int yi = oyp*4 - 1 + c;
            bool ok = okx && (yi >= 0) && (yi < GD);
            const u16* src = grid + ((size_t)(b*GD + xi)*GD + yi)*(size_t)(PZ*128) + h*25*128;
            for (int i = t; i < 432; i += 256) {   // 27 rows x 16 chunks
                int z = i >> 4, sl = i & 15;
                uint4 v = make_uint4(0u,0u,0u,0u);
                if (ok) v = *(const uint4*)(src + i*8);
                *(uint4*)(in_s + c*3456 + z*128 + ((sl ^ (z & 15)) << 3)) = v;
            }
        }
        __syncthreads();
        #pragma unroll
        for (int dy = 0; dy < 3; ++dy) {
            const int col = w + dy;
            const int s0 = (dx*3 + dy)*3;
            bf16x8 bbA[2][4], bbB[2][4], aP[2], aQ[2];
            LOADB(bbA, s0, 0);
            READA(aP, 0, 0);
            LOADB(bbB, s0, 2);
            READA(aQ, 0, 1);
            DOMFMA(aP, bbA[0]);         // step 0  (dz=0,kc=0)
            READA(aP, 0, 2);
            DOMFMA(aQ, bbA[1]);         // step 1
            LOADB(bbA, s0+1, 0);
            READA(aQ, 0, 3);
            DOMFMA(aP, bbB[0]);         // step 2
            READA(aP, 1, 0);
            DOMFMA(aQ, bbB[1]);         // step 3
            LOADB(bbB, s0+1, 2);
            READA(aQ, 1, 1);
            DOMFMA(aP, bbA[0]);         // step 4
            READA(aP, 1, 2);
            DOMFMA(aQ, bbA[1]);         // step 5
            LOADB(bbA, s0+2, 0);
            READA(aQ, 1, 3);
            DOMFMA(aP, bbB[0]);         // step 6
            READA(aP, 2, 0);
            DOMFMA(aQ, bbB[1]);         // step 7
            LOADB(bbB, s0+2, 2);
            READA(aQ, 2, 1);
            DOMFMA(aP, bbA[0]);         // step 8
            READA(aP, 2, 2);
            DOMFMA(aQ, bbA[1]);         // step 9
            READA(aQ, 2, 3);
            DOMFMA(aP, bbB[0]);         // step 10
            DOMFMA(aQ, bbB[1]);         // step 11
        }
    }

    // epilogue: store y1 rows h*25 + m (m<25) + stats partials
    if (oy < GD) {
        const size_t colbase = ((size_t)(b*GD + ox)*GD + oy)*50 + h*25;
        float s[4] = {0.f,0.f,0.f,0.f}, q[4] = {0.f,0.f,0.f,0.f};
        #pragma unroll
        for (int mf = 0; mf < 2; ++mf) {
            #pragma unroll
            for (int r = 0; r < 4; ++r) {
                int m = mf*16 + hi*4 + r;
                if (m < 25) {
                    #pragma unroll
                    for (int nf = 0; nf < 4; ++nf) {
                        float v = acc[mf][nf][r];
                        y1[(colbase + m)*64 + nf*16 + lo] = f2bf(v);
                        s[nf] += v; q[nf] += v*v;
                    }
                }
            }
        }
        #pragma unroll
        for (int nf = 0; nf < 4; ++nf) {
            atomicAdd(&red[nf*16 + lo], s[nf]);
            atomicAdd(&red[64 + nf*16 + lo], q[nf]);
        }
    }
    __syncthreads();
    if (t < 64) {
        atomicAdd(&stats[S1_SUM + t], red[t]);
        atomicAdd(&stats[S1_SQ  + t], red[64 + t]);
    }
}

// ---- BN finalize ----
__global__ void k_finalize(float* __restrict__ stats, const float* __restrict__ g,
                           const float* __restrict__ be, int C, float cnt,
                           int st_off, int sc_off, int sh_off) {
    int t = threadIdx.x;
    if (t < C) {
        float mean = stats[st_off + t] / cnt;
        float var  = stats[st_off + C + t] / cnt - mean*mean;
        float inv  = rsqrtf(var + 1e-5f);
        stats[sc_off + t] = g[t]*inv;
        stats[sh_off + t] = be[t] - mean*g[t]*inv;
    }
}

// ---- conv2 via MFMA: 3x3x3, 64->128, stride 2, pad 1; BN1+ReLU fused in staging.
// B read directly from L2 (wt2 frag-linear, 442KB resident) - no LDS weight
// stage -> LDS 26.6KB -> 4 blocks/CU.
__global__ __launch_bounds__(256, 4) void k_conv2(
        const u16* __restrict__ y1, const u16* __restrict__ wt2,
        float* __restrict__ stats, float* __restrict__ out) {
    const int ox = blockIdx.x, oyp = blockIdx.y, b = blockIdx.z;
    const int t = threadIdx.x;
    const int w = t >> 6, lane = t & 63;
    const int col = w >> 1, nh = w & 1, lo = lane & 15, hi = lane >> 4;

    __shared__ __align__(16) char pool[26624];
    u16* in2 = (u16*)pool;                // [2][52][64] bf16, slot^=((z>>1)&7)
    float* red2 = (float*)(pool + 25600); // [256] f32
    red2[t] = 0.f;

    const float* sc1 = stats + SC1;
    const float* sh1 = stats + SH1;

    f32x4 acc[2][4];
    #pragma unroll
    for (int m=0;m<2;m++){ acc[m][0]=fzero(); acc[m][1]=fzero(); acc[m][2]=fzero(); acc[m][3]=fzero(); }

    const int oy = 2*oyp + col;
    for (int dxy = 0; dxy < 9; ++dxy) {
        int dx = dxy/3, dy = dxy - dx*3;
        int xi = 2*ox + dx - 1;
        bool okx = (xi >= 0) && (xi < GD);
        __syncthreads();
        for (int i = t; i < 832; i += 256) {
            int c = (i >= 416) ? 1 : 0;
            int cc = i - c*416;
            int z = cc >> 3, sl = cc & 7;
            int oyc = 2*oyp + c;
            int yi = 2*oyc + dy - 1;
            bool ok = okx && (oyc < 25) && (yi >= 0) && (yi < GD) && (z >= 1) && (z <= 50);
            uint4 vv = make_uint4(0u,0u,0u,0u);
            if (ok) vv = *(const uint4*)(y1 + (size_t)((b*GD + xi)*GD + yi)*3200 + cc*8 - 64);
            const u16* p = (const u16*)&vv;
            u16 d8[8];
            #pragma unroll
            for (int j=0;j<8;j++) {
                int ci = sl*8 + j;
                d8[j] = ok ? f2bf(fmaxf(bf2f(p[j])*sc1[ci] + sh1[ci], 0.f)) : (u16)0;
            }
            *(uint4*)(in2 + (c*52 + z)*64 + ((sl ^ ((z>>1) & 7)) << 3)) = *(uint4*)d8;
        }
        __syncthreads();
        const u16* wsrc = wt2 + dxy*24576;
        #pragma unroll
        for (int dz = 0; dz < 3; ++dz) {
            #pragma unroll
            for (int kc = 0; kc < 2; ++kc) {
                bf16x8 a[2], bb[4];
                #pragma unroll
                for (int mf = 0; mf < 2; ++mf) {
                    int z = 2*(mf*16 + lo) + dz; z = (z > 51) ? 51 : z;
                    a[mf] = *(const bf16x8*)(in2 + (col*52 + z)*64 + (((kc*4 + hi) ^ ((z>>1) & 7)) << 3));
                }
                #pragma unroll
                for (int nf = 0; nf < 4; ++nf)
                    bb[nf] = *(const bf16x8*)(wsrc + (((dz*2 + kc)*4 + hi)*128 + (nh*4 + nf)*16 + lo)*8);
                #pragma unroll
                for (int mf = 0; mf < 2; ++mf) {
                    #pragma unroll
                    for (int nf = 0; nf < 4; ++nf)
                        acc[mf][nf] = __builtin_amdgcn_mfma_f32_16x16x32_bf16(a[mf], bb[nf], acc[mf][nf], 0, 0, 0);
                }
            }
        }
    }
    __syncthreads();
    float* trans = (float*)pool;      // [2][128][25] f32 = 25,600 B (in2 dead)
    if (oy < 25) {
        #pragma unroll
        for (int nf = 0; nf < 4; ++nf) {
            float s = 0.f, q = 0.f;
            int co = (nh*4 + nf)*16 + lo;
            #pragma unroll
            for (int mf = 0; mf < 2; ++mf) {
                #pragma unroll
                for (int r = 0; r < 4; ++r) {
                    int o = mf*16 + hi*4 + r;
                    if (o < 25) {
                        float vv = acc[mf][nf][r];
                        trans[(col*128 + co)*25 + o] = vv;
                        s += vv; q += vv*vv;
                    }
                }
            }
            atomicAdd(&red2[co], s);
            atomicAdd(&red2[128 + co], q);
        }
    }
    __syncthreads();
    if (t < 128) {
        atomicAdd(&stats[S2_SUM + t], red2[t]);
        atomicAdd(&stats[S2_SQ  + t], red2[128 + t]);
    }
    for (int i = t; i < 6400; i += 256) {
        int c = i / 3200; int r = i - c*3200;
        int co = r / 25;  int oz = r - co*25;
        int oyc = 2*oyp + c;
        if (oyc < 25)
            out[((size_t)(b*128 + co)*625 + ox*25 + oyc)*25 + oz] = trans[(c*128 + co)*25 + oz];
    }
}

// ---- BN2 + ReLU in place on d_out ----
__global__ void k_bnrelu2(float* __restrict__ out, const float* __restrict__ stats) {
    int idx = blockIdx.x*256 + threadIdx.x;
    if (idx >= 8000000) return;
    int co = (idx / 15625) & 127;
    float v = out[idx];
    out[idx] = fmaxf(v*stats[SC2 + co] + stats[SH2 + co], 0.f);
}

extern "C" void kernel_launch(void* const* d_in, const int* in_sizes, int n_in,
                              void* d_out, int out_size, void* d_ws, size_t ws_size,
                              hipStream_t stream) {
    const float* vf     = (const float*)d_in[0];
    const int*   coords = (const int*)  d_in[1];
    const float* W1 = (const float*)d_in[2];
    const float* b1 = (const float*)d_in[3];
    const float* W2 = (const float*)d_in[4];
    const float* b2 = (const float*)d_in[5];
    const float* W3 = (const float*)d_in[6];
    const float* b3 = (const float*)d_in[7];
    const float* k1 = (const float*)d_in[8];
    const float* g1 = (const float*)d_in[9];
    const float* be1= (const float*)d_in[10];
    const float* k2 = (const float*)d_in[11];
    const float* g2 = (const float*)d_in[12];
    const float* be2= (const float*)d_in[13];

    char* ws = (char*)d_ws;
    int*   owner = (int*)  (ws + OWNER_OFF);
    float* stats = (float*)(ws + STATS_OFF);
    u16*   wt1   = (u16*)  (ws + WT1_OFF);
    u16*   wt2   = (u16*)  (ws + WT2_OFF);
    u16*   vw2f  = (u16*)  (ws + VW2F_OFF);
    u16*   vw3f  = (u16*)  (ws + VW3F_OFF);
    u16*   grid  = (u16*)  (ws + GRID_OFF);
    u16*   y1    = (u16*)  (ws + Y1_OFF);
    float* out   = (float*)d_out;

    hipMemsetAsync(owner, 0xFF, (size_t)NB*CELLS*4, stream);
    hipMemsetAsync(stats, 0, 768*4, stream);
    hipMemsetAsync(grid, 0, (size_t)NB*GD*GD*PZ*128*2, stream);

    k_wt_transform<<<864, 256, 0, stream>>>(k1, k2, W2, W3, wt1, wt2, vw2f, vw3f);
    k_owner<<<(NB*NVOX+255)/256, 256, 0, stream>>>(coords, owner);
    k_vfe<<<NB*NVOX/4, 256, 0, stream>>>(vf, coords, W1, b1, b2, b3, vw2f, vw3f, owner, grid);
    k_conv1<<<dim3(GD,13,NB*2), 256, 0, stream>>>(grid, wt1, y1, stats);
    k_finalize<<<1, 64, 0, stream>>>(stats, g1, be1, 64, 500000.f, S1_SUM, SC1, SH1);
    k_conv2<<<dim3(25,13,NB), 256, 0, stream>>>(y1, wt2, stats, out);
    k_finalize<<<1, 128, 0, stream>>>(stats, g2, be2, 128, 62500.f, S2_SUM, SC2, SH2);
    k_bnrelu2<<<(8000000+255)/256, 256, 0, stream>>>(out, stats);
}